// Round 1
// baseline (118.144 us; speedup 1.0000x reference)
//
#include <hip/hip_runtime.h>

// Problem constants (B=16, S=4096, D=1024, H=16, K=15, DK=64)
constexpr int Bc   = 16;
constexpr int Sc   = 4096;
constexpr int Hc   = 16;
constexpr int Kc   = 15;
constexpr int PAD  = 7;
constexpr int DKc  = 64;
constexpr int LSTRIDE = DKc + 2 * PAD;  // 78 floats per padded LDS row
constexpr int ROWS_PER_BLOCK = 64;
constexpr int THREADS = 256;

__global__ __launch_bounds__(THREADS) void lwconv_kernel(
    const float* __restrict__ x, const float* __restrict__ W,
    const float* __restrict__ bias, float* __restrict__ out)
{
    __shared__ float lds[ROWS_PER_BLOCK * LSTRIDE];  // ~19.5 KB
    const int tid = threadIdx.x;
    const long long block_row0 = (long long)blockIdx.x * ROWS_PER_BLOCK;

    // ---- stage 64 rows (4096 floats, 16 KB) via float4, coalesced ----
    const float4* xin = (const float4*)(x + block_row0 * DKc);
    #pragma unroll
    for (int j = 0; j < 4; ++j) {
        int i = j * THREADS + tid;          // float4 index in [0,1024)
        float4 v = xin[i];
        int e   = i * 4;
        int row = e >> 6;                    // /64
        int col = e & 63;
        float* p = &lds[row * LSTRIDE + PAD + col];
        p[0] = v.x; p[1] = v.y; p[2] = v.z; p[3] = v.w;
    }
    // ---- zero the 7-wide pads on both sides of each row ----
    for (int p = tid; p < ROWS_PER_BLOCK * 2 * PAD; p += THREADS) {
        int row = p / (2 * PAD);
        int c   = p % (2 * PAD);
        lds[row * LSTRIDE + (c < PAD ? c : DKc + c)] = 0.f;
    }

    // ---- block-uniform head / batch / sequence decode ----
    // rid = (b*H + h)*S + s'  ->  h = (rid>>12)&15, b = rid>>16, s' = rid&4095
    const int h    = (int)((block_row0 >> 12) & (Hc - 1));
    const int bidx = (int)(block_row0 >> 16);
    const long long sp0 = block_row0 & (Sc - 1);

    // ---- softmax(W[h]) into registers (redundant per thread, scalarizes) ----
    float w[Kc];
    float wmax = -1e30f;
    #pragma unroll
    for (int t = 0; t < Kc; ++t) { w[t] = W[h * Kc + t]; wmax = fmaxf(wmax, w[t]); }
    float wsum = 0.f;
    #pragma unroll
    for (int t = 0; t < Kc; ++t) { w[t] = __expf(w[t] - wmax); wsum += w[t]; }
    const float winv = 1.f / wsum;
    const float bv   = bias[h];

    __syncthreads();

    // ---- compute + store: out base for this block is one contiguous 16 KB span ----
    const long long out_base = ((long long)(h * Bc + bidx) * Sc + sp0) * DKc;
    #pragma unroll
    for (int j = 0; j < 16; ++j) {
        int e   = j * THREADS + tid;        // [0,4096): one wave = one row per j
        int row = e >> 6;
        int k   = e & 63;
        const float* p = &lds[row * LSTRIDE + k];  // p[t] = x_row[k - 7 + t]
        float acc = 0.f;
        #pragma unroll
        for (int t = 0; t < Kc; ++t) acc = fmaf(w[t], p[t], acc);
        acc = acc * winv + bv;               // fold softmax normalization into epilogue
        out[out_base + e] = fmaxf(acc, 0.f);
    }
}

extern "C" void kernel_launch(void* const* d_in, const int* in_sizes, int n_in,
                              void* d_out, int out_size, void* d_ws, size_t ws_size,
                              hipStream_t stream) {
    const float* x    = (const float*)d_in[0];
    const float* W    = (const float*)d_in[1];
    const float* bias = (const float*)d_in[2];
    float* out        = (float*)d_out;

    const long long total_rows = (long long)Bc * Hc * Sc;      // 1,048,576
    const int grid = (int)(total_rows / ROWS_PER_BLOCK);       // 16,384
    lwconv_kernel<<<grid, THREADS, 0, stream>>>(x, W, bias, out);
}

// Round 2
// 114.754 us; speedup vs baseline: 1.0295x; 1.0295x over previous
//
#include <hip/hip_runtime.h>

// B=16, S=4096, D=1024, H=16, K=15, DK=64
constexpr int Bc   = 16;
constexpr int Sc   = 4096;
constexpr int Hc   = 16;
constexpr int Kc   = 15;
constexpr int DKc  = 64;
constexpr int FPAD = 8;                  // front pad (window needs c0-8, 16B aligned)
constexpr int LSTRIDE = FPAD + DKc + 8;  // 80 floats/row: front 8 + 64 + back 8
constexpr int ROWS = 64;
constexpr int THREADS = 256;

__global__ __launch_bounds__(THREADS) void lwconv_kernel(
    const float* __restrict__ x, const float* __restrict__ W,
    const float* __restrict__ bias, float* __restrict__ out)
{
    __shared__ float lds[ROWS * LSTRIDE];  // 20 KB
    const int tid = threadIdx.x;
    const long long row0 = (long long)blockIdx.x * ROWS;

    // ---- stage 64 rows (16 KB) coalesced, float4 ----
    const float4* xin = (const float4*)(x + row0 * DKc);
    #pragma unroll
    for (int j = 0; j < 4; ++j) {
        int i = j * THREADS + tid;           // float4 idx [0,1024)
        float4 v = xin[i];
        int e = i * 4, r = e >> 6, c = e & 63;
        *(float4*)&lds[r * LSTRIDE + FPAD + c] = v;
    }
    // ---- zero pads: 4 float4 per row (2 front, 2 back), 256 total = 1/thread ----
    {
        int r = tid >> 2, which = tid & 3;
        int off = (which < 2) ? which * 4 : (FPAD + DKc) + (which - 2) * 4;
        *(float4*)&lds[r * LSTRIDE + off] = make_float4(0.f, 0.f, 0.f, 0.f);
    }

    // ---- block-uniform decode: rid = (b*H + h)*S + s' ----
    const int h    = (int)((row0 >> 12) & (Hc - 1));
    const int bidx = (int)(row0 >> 16);
    const long long sp0 = row0 & (Sc - 1);

    // ---- softmax(W[h]) with 1/sum folded into taps; bias as acc init ----
    float w[Kc];
    float wmax = -1e30f;
    #pragma unroll
    for (int t = 0; t < Kc; ++t) { w[t] = W[h * Kc + t]; wmax = fmaxf(wmax, w[t]); }
    float wsum = 0.f;
    #pragma unroll
    for (int t = 0; t < Kc; ++t) { w[t] = __expf(w[t] - wmax); wsum += w[t]; }
    const float winv = 1.f / wsum;
    #pragma unroll
    for (int t = 0; t < Kc; ++t) w[t] *= winv;
    const float bv = bias[h];

    __syncthreads();

    // ---- compute: 4 consecutive outputs/thread/iter via register sliding window ----
    const long long out_base = ((long long)(h * Bc + bidx) * Sc + sp0) * DKc;
    float4* outv = (float4*)(out + out_base);
    #pragma unroll
    for (int j = 0; j < 4; ++j) {
        int g  = j * THREADS + tid;          // output float4 idx [0,1024) -> coalesced store
        int r  = g >> 4;
        int c0 = (g & 15) * 4;
        const float* p = &lds[r * LSTRIDE + c0];  // p[i] = x_row[c0 - 8 + i]
        float f[20];
        #pragma unroll
        for (int i = 0; i < 5; ++i) *(float4*)&f[i * 4] = *(const float4*)&p[i * 4];
        float a0 = bv, a1 = bv, a2 = bv, a3 = bv;
        #pragma unroll
        for (int t = 0; t < Kc; ++t) {       // out[c0+o] needs x[c0+o-7+t] = f[o+1+t]
            a0 = fmaf(w[t], f[1 + t], a0);
            a1 = fmaf(w[t], f[2 + t], a1);
            a2 = fmaf(w[t], f[3 + t], a2);
            a3 = fmaf(w[t], f[4 + t], a3);
        }
        float4 o;
        o.x = fmaxf(a0, 0.f); o.y = fmaxf(a1, 0.f);
        o.z = fmaxf(a2, 0.f); o.w = fmaxf(a3, 0.f);
        outv[g] = o;
    }
}

extern "C" void kernel_launch(void* const* d_in, const int* in_sizes, int n_in,
                              void* d_out, int out_size, void* d_ws, size_t ws_size,
                              hipStream_t stream) {
    const float* x    = (const float*)d_in[0];
    const float* W    = (const float*)d_in[1];
    const float* bias = (const float*)d_in[2];
    float* out        = (float*)d_out;

    const long long total_rows = (long long)Bc * Hc * Sc;   // 1,048,576
    const int grid = (int)(total_rows / ROWS);              // 16,384
    lwconv_kernel<<<grid, THREADS, 0, stream>>>(x, W, bias, out);
}

// Round 4
// 88.162 us; speedup vs baseline: 1.3401x; 1.3016x over previous
//
#include <hip/hip_runtime.h>

// B=16, S=4096, D=1024, H=16, K=15, DK=64
constexpr int Bc   = 16;
constexpr int Sc   = 4096;
constexpr int Hc   = 16;
constexpr int Kc   = 15;
constexpr int DKc  = 64;
constexpr int ROWS = 64;        // rows per block
constexpr int THREADS = 256;

typedef float f32x4 __attribute__((ext_vector_type(4)));

__global__ __launch_bounds__(THREADS) void lwconv_kernel(
    const float* __restrict__ x, const float* __restrict__ W,
    const float* __restrict__ bias, float* __restrict__ out)
{
    const int tid = threadIdx.x;
    const long long row0 = (long long)blockIdx.x * ROWS;

    // block-uniform decode: rid = (b*H + h)*S + s'
    const int h    = (int)((row0 >> 12) & (Hc - 1));
    const int bidx = (int)(row0 >> 16);
    const long long sp0 = row0 & (Sc - 1);

    // softmax(W[h]); 1/sum folded into taps, bias as accumulator init (scalarizes: h uniform)
    float w[Kc];
    float wmax = -1e30f;
    #pragma unroll
    for (int t = 0; t < Kc; ++t) { w[t] = W[h * Kc + t]; wmax = fmaxf(wmax, w[t]); }
    float wsum = 0.f;
    #pragma unroll
    for (int t = 0; t < Kc; ++t) { w[t] = __expf(w[t] - wmax); wsum += w[t]; }
    const float winv = 1.f / wsum;
    #pragma unroll
    for (int t = 0; t < Kc; ++t) w[t] *= winv;
    const float bv = bias[h];

    const long long in_base  = row0 * DKc;                                  // float idx
    const long long out_base = ((long long)(h * Bc + bidx) * Sc + sp0) * DKc;
    const long long Ntot     = (long long)Bc * Hc * Sc * DKc;               // 67.1M floats
    const bool interior = (blockIdx.x != 0) && (blockIdx.x != gridDim.x - 1);

    const f32x4* __restrict__ xv = (const f32x4*)x;   // all window offsets are 16B-aligned
    f32x4* outv = (f32x4*)(out + out_base);

    // c0 = starting column of this thread's 4 outputs; loop-invariant (256 % 16 == 0)
    const int c0 = (tid & 15) * 4;
    // window element f[j] holds column c0-8+j; zero-mask out-of-row groups (quad-aligned)
    const float mA = (c0 >= 8)  ? 1.f : 0.f;   // f[0..3]  : cols c0-8..c0-5
    const float mB = (c0 >= 4)  ? 1.f : 0.f;   // f[4..7]  : cols c0-4..c0-1
    const float mC = (c0 <= 56) ? 1.f : 0.f;   // f[12..15]: cols c0+4..c0+7
    const float mD = (c0 <= 52) ? 1.f : 0.f;   // f[16..19]: cols c0+8..c0+11

    #pragma unroll
    for (int j = 0; j < 4; ++j) {
        const int g = j * THREADS + tid;            // float4 unit [0,1024)
        const int r = g >> 4;                       // row within block
        const long long off = in_base + (long long)r * DKc + c0 - 8;  // %4 == 0
        float f[20];
        if (interior) {
            #pragma unroll
            for (int i = 0; i < 5; ++i)
                *(f32x4*)&f[4 * i] = xv[(off >> 2) + i];
        } else {
            #pragma unroll
            for (int i = 0; i < 5; ++i) {
                long long o = off + 4 * i;
                f32x4 v = (f32x4)(0.f);
                if (o >= 0 && o + 4 <= Ntot) v = xv[o >> 2];
                *(f32x4*)&f[4 * i] = v;
            }
        }
        f[0]  *= mA; f[1]  *= mA; f[2]  *= mA; f[3]  *= mA;
        f[4]  *= mB; f[5]  *= mB; f[6]  *= mB; f[7]  *= mB;
        f[12] *= mC; f[13] *= mC; f[14] *= mC; f[15] *= mC;
        f[16] *= mD; f[17] *= mD; f[18] *= mD; f[19] *= mD;

        float a0 = bv, a1 = bv, a2 = bv, a3 = bv;
        #pragma unroll
        for (int t = 0; t < Kc; ++t) {              // out[c0+o] uses f[o+1+t]
            a0 = fmaf(w[t], f[1 + t], a0);
            a1 = fmaf(w[t], f[2 + t], a1);
            a2 = fmaf(w[t], f[3 + t], a2);
            a3 = fmaf(w[t], f[4 + t], a3);
        }
        f32x4 o4;
        o4.x = fmaxf(a0, 0.f); o4.y = fmaxf(a1, 0.f);
        o4.z = fmaxf(a2, 0.f); o4.w = fmaxf(a3, 0.f);
        __builtin_nontemporal_store(o4, &outv[g]);  // zero-reuse output: don't thrash L2
    }
}

extern "C" void kernel_launch(void* const* d_in, const int* in_sizes, int n_in,
                              void* d_out, int out_size, void* d_ws, size_t ws_size,
                              hipStream_t stream) {
    const float* x    = (const float*)d_in[0];
    const float* W    = (const float*)d_in[1];
    const float* bias = (const float*)d_in[2];
    float* out        = (float*)d_out;

    const long long total_rows = (long long)Bc * Hc * Sc;   // 1,048,576
    const int grid = (int)(total_rows / ROWS);              // 16,384
    lwconv_kernel<<<grid, THREADS, 0, stream>>>(x, W, bias, out);
}